// Round 1
// baseline (320.362 us; speedup 1.0000x reference)
//
#include <hip/hip_runtime.h>
#include <stdint.h>

#define S_LEN 2048
#define BATCH 2
#define DM 1024
#define NH 16
#define DH 64
#define MROWS 4096  // BATCH * S_LEN

typedef unsigned short u16;
typedef __attribute__((ext_vector_type(8))) short bf16x8;
typedef __attribute__((ext_vector_type(4))) float f32x4;

__device__ inline u16 f2bf(float f) {
  union { float f; unsigned u; } v; v.f = f;
  unsigned u = v.u;
  unsigned r = u + 0x7fffu + ((u >> 16) & 1u);
  return (u16)(r >> 16);
}

// ---------------- fp32 -> bf16 conversion for x, Wq, Wk, Wv, Wo ----------------
__global__ void convert_k(const float* __restrict__ x, const float* __restrict__ wq,
                          const float* __restrict__ wk, const float* __restrict__ wv,
                          const float* __restrict__ wo, u16* __restrict__ xb,
                          u16* __restrict__ wb) {
  int i = blockIdx.x * blockDim.x + threadIdx.x;
  const int total = (MROWS * DM + 4 * DM * DM) / 4;  // 2,097,152 float4 groups
  if (i >= total) return;
  int e = i * 4;
  const float* src;
  u16* dst;
  if (e < MROWS * DM) {
    src = x + e; dst = xb + e;
  } else {
    int j = e - MROWS * DM;
    int w = j >> 20;
    int o = j & ((1 << 20) - 1);
    src = (w == 0) ? wq + o : (w == 1) ? wk + o : (w == 2) ? wv + o : wo + o;
    dst = wb + j;
  }
  float4 v = *(const float4*)src;
  uint2 r;
  r.x = (unsigned)f2bf(v.x) | ((unsigned)f2bf(v.y) << 16);
  r.y = (unsigned)f2bf(v.z) | ((unsigned)f2bf(v.w) << 16);
  *(uint2*)dst = r;
}

// ---------------- RoPE cos/sin table [S][32] ----------------
__global__ void rope_k(float2* __restrict__ tab) {
  int i = blockIdx.x * blockDim.x + threadIdx.x;
  if (i >= S_LEN * 32) return;
  int s = i >> 5, p = i & 31;
  float inv = expf(-(float)p * 0.28782313662425575f);  // ln(10000)/32
  float a = (float)s * inv;
  tab[i] = make_float2(cosf(a), sinf(a));
}

// ---------------- GEMM: C = A @ W^T + bias, fused epilogues ----------------
// mode 0: Q  -> rope, *0.125, bf16 [B,H,S,Dh]
// mode 1: K  -> rope, bf16 [B,H,S,Dh]
// mode 2: V  -> bf16 transposed [B,H,Dh,S]
// mode 3: O  -> fp32 [M, DM]
__launch_bounds__(256)
__global__ void gemm_k(const u16* __restrict__ A,
                       const u16* __restrict__ w0, const u16* __restrict__ w1,
                       const u16* __restrict__ w2,
                       const float* __restrict__ b0, const float* __restrict__ b1,
                       const float* __restrict__ b2,
                       const float2* __restrict__ rope,
                       void* __restrict__ o0, void* __restrict__ o1, void* __restrict__ o2,
                       int mode0) {
  const int mode = mode0 + (int)(blockIdx.x >> 8);
  const int tile = blockIdx.x & 255;
  const int mt = tile >> 3, nt = tile & 7;
  const int mbase = mt * 128, nbase = nt * 128;
  const u16* W = (mode == 1) ? w1 : (mode == 2) ? w2 : w0;
  const float* bias = (mode == 1) ? b1 : (mode == 2) ? b2 : b0;
  void* outp = (mode == 1) ? o1 : (mode == 2) ? o2 : o0;

  __shared__ u16 As[128 * 40];  // padded row stride 40 (2-way bank aliasing = free)
  __shared__ u16 Bs[128 * 40];

  const int t = threadIdx.x;
  const int lane = t & 63, wvi = t >> 6;
  const int lr = lane & 15, lg = lane >> 4;
  const int wm = (wvi >> 1) * 64, wn = (wvi & 1) * 64;

  f32x4 acc[4][4] = {};
  const int srow = t >> 2;        // 0..63
  const int scol = (t & 3) * 8;   // 0,8,16,24

  for (int kk = 0; kk < DM; kk += 32) {
    bf16x8 a0 = *(const bf16x8*)(A + (size_t)(mbase + srow) * DM + kk + scol);
    bf16x8 a1 = *(const bf16x8*)(A + (size_t)(mbase + 64 + srow) * DM + kk + scol);
    bf16x8 g0 = *(const bf16x8*)(W + (size_t)(nbase + srow) * DM + kk + scol);
    bf16x8 g1 = *(const bf16x8*)(W + (size_t)(nbase + 64 + srow) * DM + kk + scol);
    __syncthreads();
    *(bf16x8*)&As[srow * 40 + scol] = a0;
    *(bf16x8*)&As[(64 + srow) * 40 + scol] = a1;
    *(bf16x8*)&Bs[srow * 40 + scol] = g0;
    *(bf16x8*)&Bs[(64 + srow) * 40 + scol] = g1;
    __syncthreads();
    bf16x8 af[4], bfr[4];
#pragma unroll
    for (int mi = 0; mi < 4; mi++)
      af[mi] = *(const bf16x8*)&As[(wm + mi * 16 + lr) * 40 + lg * 8];
#pragma unroll
    for (int ni = 0; ni < 4; ni++)
      bfr[ni] = *(const bf16x8*)&Bs[(wn + ni * 16 + lr) * 40 + lg * 8];
#pragma unroll
    for (int mi = 0; mi < 4; mi++)
#pragma unroll
      for (int ni = 0; ni < 4; ni++)
        acc[mi][ni] = __builtin_amdgcn_mfma_f32_16x16x32_bf16(af[mi], bfr[ni], acc[mi][ni], 0, 0, 0);
  }

#pragma unroll
  for (int ni = 0; ni < 4; ni++) {
    const int col = nbase + wn + ni * 16 + lr;
    const float bv = bias[col];
#pragma unroll
    for (int mi = 0; mi < 4; mi++) {
      const int row0 = mbase + wm + mi * 16 + lg * 4;
      f32x4 v = acc[mi][ni];
#pragma unroll
      for (int r = 0; r < 4; r++) {
        float val = v[r] + bv;
        const int row = row0 + r;
        if (mode <= 1) {
          float nb = __shfl_xor(val, 1);
          const int d = col & 63, p = d >> 1, s = row & (S_LEN - 1);
          float2 cs = rope[s * 32 + p];
          float ov = (d & 1) ? (nb * cs.y + val * cs.x) : (val * cs.x - nb * cs.y);
          if (mode == 0) ov *= 0.125f;  // fold 1/sqrt(Dh)
          const int b = row >> 11, h = col >> 6;
          ((u16*)outp)[((size_t)(b * NH + h) * S_LEN + s) * DH + d] = f2bf(ov);
        } else if (mode == 2) {
          const int b = row >> 11, h = col >> 6, d = col & 63, s = row & (S_LEN - 1);
          ((u16*)outp)[((size_t)(b * NH + h) * DH + d) * S_LEN + s] = f2bf(val);
        } else {
          ((float*)outp)[(size_t)row * DM + col] = val;
        }
      }
    }
  }
}

// ---------------- causal flash attention ----------------
// grid: bh (32) x qblock (32); 4 waves/block, each owns 16 q-rows, no barriers.
__launch_bounds__(256)
__global__ void attn_k(const u16* __restrict__ Q, const u16* __restrict__ K,
                       const u16* __restrict__ Vt, u16* __restrict__ Oo) {
  const int bh = blockIdx.x >> 5;
  const int qb = blockIdx.x & 31;
  const int t = threadIdx.x;
  const int lane = t & 63, wvi = t >> 6;
  const int lr = lane & 15, lg = lane >> 4;
  const int qw = qb * 64 + wvi * 16;

  __shared__ u16 P[4][16 * 40];
  u16* Pw = (u16*)P[wvi];

  const size_t qoff = ((size_t)bh * S_LEN + qw + lr) * DH + lg * 8;
  bf16x8 q0 = *(const bf16x8*)(Q + qoff);
  bf16x8 q1 = *(const bf16x8*)(Q + qoff + 32);

  f32x4 o[4] = {};
  float mrun[4], lrun[4];
#pragma unroll
  for (int r = 0; r < 4; r++) { mrun[r] = -__builtin_inff(); lrun[r] = 0.f; }
  const f32x4 zero = {};

  for (int kv = 0; kv <= qw + 15; kv += 32) {
    const size_t k0 = ((size_t)bh * S_LEN + kv + lr) * DH + lg * 8;
    bf16x8 k00 = *(const bf16x8*)(K + k0);
    bf16x8 k01 = *(const bf16x8*)(K + k0 + 32);
    bf16x8 k10 = *(const bf16x8*)(K + k0 + 16 * DH);
    bf16x8 k11 = *(const bf16x8*)(K + k0 + 16 * DH + 32);
    f32x4 s0 = __builtin_amdgcn_mfma_f32_16x16x32_bf16(q0, k00, zero, 0, 0, 0);
    s0 = __builtin_amdgcn_mfma_f32_16x16x32_bf16(q1, k01, s0, 0, 0, 0);
    f32x4 s1 = __builtin_amdgcn_mfma_f32_16x16x32_bf16(q0, k10, zero, 0, 0, 0);
    s1 = __builtin_amdgcn_mfma_f32_16x16x32_bf16(q1, k11, s1, 0, 0, 0);

    float corr[4];
#pragma unroll
    for (int r = 0; r < 4; r++) {
      const int row = qw + lg * 4 + r;
      float a0 = ((kv + lr) <= row) ? s0[r] : -__builtin_inff();
      float a1 = ((kv + 16 + lr) <= row) ? s1[r] : -__builtin_inff();
      float mx = fmaxf(a0, a1);
      mx = fmaxf(mx, __shfl_xor(mx, 1));
      mx = fmaxf(mx, __shfl_xor(mx, 2));
      mx = fmaxf(mx, __shfl_xor(mx, 4));
      mx = fmaxf(mx, __shfl_xor(mx, 8));
      const float mn = fmaxf(mrun[r], mx);
      const float c = __expf(mrun[r] - mn);
      const float p0 = __expf(a0 - mn);
      const float p1 = __expf(a1 - mn);
      float sum = p0 + p1;
      sum += __shfl_xor(sum, 1);
      sum += __shfl_xor(sum, 2);
      sum += __shfl_xor(sum, 4);
      sum += __shfl_xor(sum, 8);
      lrun[r] = lrun[r] * c + sum;
      mrun[r] = mn;
      corr[r] = c;
      Pw[(lg * 4 + r) * 40 + lr] = f2bf(p0);
      Pw[(lg * 4 + r) * 40 + lr + 16] = f2bf(p1);
    }
#pragma unroll
    for (int dt = 0; dt < 4; dt++)
#pragma unroll
      for (int r = 0; r < 4; r++) o[dt][r] *= corr[r];

    __builtin_amdgcn_wave_barrier();  // keep compiler from moving the read above the writes
    bf16x8 pf = *(const bf16x8*)&Pw[lr * 40 + lg * 8];
#pragma unroll
    for (int dt = 0; dt < 4; dt++) {
      bf16x8 vf = *(const bf16x8*)(Vt + ((size_t)bh * DH + dt * 16 + lr) * S_LEN + kv + lg * 8);
      o[dt] = __builtin_amdgcn_mfma_f32_16x16x32_bf16(pf, vf, o[dt], 0, 0, 0);
    }
  }

  const int b = bh >> 4, h = bh & 15;
#pragma unroll
  for (int dt = 0; dt < 4; dt++)
#pragma unroll
    for (int r = 0; r < 4; r++) {
      const int s = qw + lg * 4 + r;
      const int d = dt * 16 + lr;
      float val = o[dt][r] / lrun[r];
      Oo[((size_t)b * S_LEN + s) * DM + h * DH + d] = f2bf(val);
    }
}

// ---------------- host launcher ----------------
extern "C" void kernel_launch(void* const* d_in, const int* in_sizes, int n_in,
                              void* d_out, int out_size, void* d_ws, size_t ws_size,
                              hipStream_t stream) {
  const float* x  = (const float*)d_in[0];
  const float* Wq = (const float*)d_in[1];
  const float* bq = (const float*)d_in[2];
  const float* Wk = (const float*)d_in[3];
  const float* bk = (const float*)d_in[4];
  const float* Wv = (const float*)d_in[5];
  const float* bv = (const float*)d_in[6];
  const float* Wo = (const float*)d_in[7];
  const float* bo = (const float*)d_in[8];

  char* ws = (char*)d_ws;
  u16* xb    = (u16*)(ws);                 // 8 MB  [4096,1024] bf16
  u16* wb    = (u16*)(ws + (8u << 20));    // 8 MB  Wq,Wk,Wv,Wo bf16
  u16* Qb    = (u16*)(ws + (16u << 20));   // 8 MB  [B,H,S,Dh]
  u16* Kb    = (u16*)(ws + (24u << 20));   // 8 MB  [B,H,S,Dh]
  u16* Vtb   = (u16*)(ws + (32u << 20));   // 8 MB  [B,H,Dh,S]
  u16* AOb   = (u16*)(ws + (40u << 20));   // 8 MB  [B*S, DM]
  float2* rt = (float2*)(ws + (48u << 20)); // 512 KB rope table

  convert_k<<<8192, 256, 0, stream>>>(x, Wq, Wk, Wv, Wo, xb, wb);
  rope_k<<<256, 256, 0, stream>>>(rt);
  gemm_k<<<768, 256, 0, stream>>>(xb, wb, wb + (1u << 20), wb + (2u << 20),
                                  bq, bk, bv, rt, Qb, Kb, Vtb, 0);
  attn_k<<<1024, 256, 0, stream>>>(Qb, Kb, Vtb, AOb);
  gemm_k<<<256, 256, 0, stream>>>(AOb, wb + (3u << 20), wb + (3u << 20), wb + (3u << 20),
                                  bo, bo, bo, rt, d_out, d_out, d_out, 3);
}

// Round 2
// 222.876 us; speedup vs baseline: 1.4374x; 1.4374x over previous
//
#include <hip/hip_runtime.h>
#include <stdint.h>

#define S_LEN 2048
#define BATCH 2
#define DM 1024
#define NH 16
#define DH 64
#define MROWS 4096  // BATCH * S_LEN

typedef unsigned short u16;
typedef unsigned int u32;
typedef __attribute__((ext_vector_type(8))) short bf16x8;
typedef __attribute__((ext_vector_type(4))) float f32x4;
typedef __attribute__((ext_vector_type(2))) unsigned u32x2;

__device__ inline u16 f2bf(float f) {
  union { float f; unsigned u; } v; v.f = f;
  unsigned u = v.u;
  unsigned r = u + 0x7fffu + ((u >> 16) & 1u);
  return (u16)(r >> 16);
}

__device__ inline u32 pkbf(float lo, float hi) {
  u32 r;
  asm("v_cvt_pk_bf16_f32 %0, %1, %2" : "=v"(r) : "v"(lo), "v"(hi));
  return r;
}

// ---------------- fp32 -> bf16 conversion for x, Wq, Wk, Wv, Wo ----------------
__global__ void convert_k(const float* __restrict__ x, const float* __restrict__ wq,
                          const float* __restrict__ wk, const float* __restrict__ wv,
                          const float* __restrict__ wo, u16* __restrict__ xb,
                          u16* __restrict__ wb) {
  int i = blockIdx.x * blockDim.x + threadIdx.x;
  const int total = (MROWS * DM + 4 * DM * DM) / 4;  // 2,097,152 float4 groups
  if (i >= total) return;
  int e = i * 4;
  const float* src;
  u16* dst;
  if (e < MROWS * DM) {
    src = x + e; dst = xb + e;
  } else {
    int j = e - MROWS * DM;
    int w = j >> 20;
    int o = j & ((1 << 20) - 1);
    src = (w == 0) ? wq + o : (w == 1) ? wk + o : (w == 2) ? wv + o : wo + o;
    dst = wb + j;
  }
  float4 v = *(const float4*)src;
  uint2 r;
  r.x = (unsigned)f2bf(v.x) | ((unsigned)f2bf(v.y) << 16);
  r.y = (unsigned)f2bf(v.z) | ((unsigned)f2bf(v.w) << 16);
  *(uint2*)dst = r;
}

// ---------------- RoPE cos/sin table [S][32] ----------------
__global__ void rope_k(float2* __restrict__ tab) {
  int i = blockIdx.x * blockDim.x + threadIdx.x;
  if (i >= S_LEN * 32) return;
  int s = i >> 5, p = i & 31;
  float inv = expf(-(float)p * 0.28782313662425575f);  // ln(10000)/32
  float a = (float)s * inv;
  tab[i] = make_float2(cosf(a), sinf(a));
}

// ---------------- GEMM: C = A @ W^T + bias, fused epilogues ----------------
// mode 0: Q  -> rope, *0.125*log2e, bf16 [B,H,S,Dh]   (log2e folded so attn uses exp2)
// mode 1: K  -> rope, bf16 [B,H,S,Dh]
// mode 2: V  -> bf16 transposed [B,H,Dh,S]
// mode 3: O  -> fp32 [M, DM]
__launch_bounds__(256)
__global__ void gemm_k(const u16* __restrict__ A,
                       const u16* __restrict__ w0, const u16* __restrict__ w1,
                       const u16* __restrict__ w2,
                       const float* __restrict__ b0, const float* __restrict__ b1,
                       const float* __restrict__ b2,
                       const float2* __restrict__ rope,
                       void* __restrict__ o0, void* __restrict__ o1, void* __restrict__ o2,
                       int mode0) {
  const int mode = mode0 + (int)(blockIdx.x >> 8);
  const int tile = blockIdx.x & 255;
  const int mt = tile >> 3, nt = tile & 7;
  const int mbase = mt * 128, nbase = nt * 128;
  const u16* W = (mode == 1) ? w1 : (mode == 2) ? w2 : w0;
  const float* bias = (mode == 1) ? b1 : (mode == 2) ? b2 : b0;
  void* outp = (mode == 1) ? o1 : (mode == 2) ? o2 : o0;

  __shared__ u16 As[128 * 40];  // padded row stride 40 (2-way bank aliasing = free)
  __shared__ u16 Bs[128 * 40];

  const int t = threadIdx.x;
  const int lane = t & 63, wvi = t >> 6;
  const int lr = lane & 15, lg = lane >> 4;
  const int wm = (wvi >> 1) * 64, wn = (wvi & 1) * 64;

  f32x4 acc[4][4] = {};
  const int srow = t >> 2;        // 0..63
  const int scol = (t & 3) * 8;   // 0,8,16,24

  for (int kk = 0; kk < DM; kk += 32) {
    bf16x8 a0 = *(const bf16x8*)(A + (size_t)(mbase + srow) * DM + kk + scol);
    bf16x8 a1 = *(const bf16x8*)(A + (size_t)(mbase + 64 + srow) * DM + kk + scol);
    bf16x8 g0 = *(const bf16x8*)(W + (size_t)(nbase + srow) * DM + kk + scol);
    bf16x8 g1 = *(const bf16x8*)(W + (size_t)(nbase + 64 + srow) * DM + kk + scol);
    __syncthreads();
    *(bf16x8*)&As[srow * 40 + scol] = a0;
    *(bf16x8*)&As[(64 + srow) * 40 + scol] = a1;
    *(bf16x8*)&Bs[srow * 40 + scol] = g0;
    *(bf16x8*)&Bs[(64 + srow) * 40 + scol] = g1;
    __syncthreads();
    bf16x8 af[4], bfr[4];
#pragma unroll
    for (int mi = 0; mi < 4; mi++)
      af[mi] = *(const bf16x8*)&As[(wm + mi * 16 + lr) * 40 + lg * 8];
#pragma unroll
    for (int ni = 0; ni < 4; ni++)
      bfr[ni] = *(const bf16x8*)&Bs[(wn + ni * 16 + lr) * 40 + lg * 8];
#pragma unroll
    for (int mi = 0; mi < 4; mi++)
#pragma unroll
      for (int ni = 0; ni < 4; ni++)
        acc[mi][ni] = __builtin_amdgcn_mfma_f32_16x16x32_bf16(af[mi], bfr[ni], acc[mi][ni], 0, 0, 0);
  }

#pragma unroll
  for (int ni = 0; ni < 4; ni++) {
    const int col = nbase + wn + ni * 16 + lr;
    const float bv = bias[col];
#pragma unroll
    for (int mi = 0; mi < 4; mi++) {
      const int row0 = mbase + wm + mi * 16 + lg * 4;
      f32x4 v = acc[mi][ni];
#pragma unroll
      for (int r = 0; r < 4; r++) {
        float val = v[r] + bv;
        const int row = row0 + r;
        if (mode <= 1) {
          float nb = __shfl_xor(val, 1);
          const int d = col & 63, p = d >> 1, s = row & (S_LEN - 1);
          float2 cs = rope[s * 32 + p];
          float ov = (d & 1) ? (nb * cs.y + val * cs.x) : (val * cs.x - nb * cs.y);
          if (mode == 0) ov *= 0.18033688011112042f;  // 1/sqrt(Dh) * log2(e)
          const int b = row >> 11, h = col >> 6;
          ((u16*)outp)[((size_t)(b * NH + h) * S_LEN + s) * DH + d] = f2bf(ov);
        } else if (mode == 2) {
          const int b = row >> 11, h = col >> 6, d = col & 63, s = row & (S_LEN - 1);
          ((u16*)outp)[((size_t)(b * NH + h) * DH + d) * S_LEN + s] = f2bf(val);
        } else {
          ((float*)outp)[(size_t)row * DM + col] = val;
        }
      }
    }
  }
}

// ---------------- causal flash attention, swapped-operand softmax ----------------
// Scores computed as S^T = mfma(K, Q): col = q (lane&15), rows = kv (regs).
// kv-reduction is in-register (+2 shfl_xor); O held transposed (O^T = mfma(Vt, P^T))
// so softmax stats and accumulator live in the SAME lane.
// grid: 2048 blocks x 128 thr; 2 waves/block; wave owns one 16-row q-tile,
// tiles issued longest-first for causal load balance.
__launch_bounds__(128)
__global__ void attn_k(const u16* __restrict__ Q, const u16* __restrict__ K,
                       const u16* __restrict__ Vt, u16* __restrict__ Oo) {
  const int bh = blockIdx.x & 31;
  const int pr = blockIdx.x >> 5;           // 0..63
  const int wv = threadIdx.x >> 6;          // wave 0/1
  const int lane = threadIdx.x & 63;
  const int lr = lane & 15, lg = lane >> 4;
  const int tile = 127 - (pr * 2 + wv);     // longest first
  const int qbase = tile * 16;

  __shared__ u16 Pl_s[2][16 * 40];
  u16* Pl = Pl_s[wv];
  u32* Plw = (u32*)Pl;

  const size_t qoff = ((size_t)bh * S_LEN + qbase + lr) * DH + lg * 8;
  const bf16x8 q0 = *(const bf16x8*)(Q + qoff);
  const bf16x8 q1 = *(const bf16x8*)(Q + qoff + 32);

  f32x4 o[4] = {};
  float m = -__builtin_inff(), l = 0.f;
  const f32x4 zero = {};
  const int nsteps = (qbase + 47) >> 5;

  for (int step = 0; step < nsteps; ++step) {
    const int kv = step << 5;
    // ---- QK^T (swapped): A = K rows, B = Q rows ----
    const size_t k0 = ((size_t)bh * S_LEN + kv + lr) * DH + lg * 8;
    bf16x8 k00 = *(const bf16x8*)(K + k0);
    bf16x8 k01 = *(const bf16x8*)(K + k0 + 32);
    bf16x8 k10 = *(const bf16x8*)(K + k0 + 16 * DH);
    bf16x8 k11 = *(const bf16x8*)(K + k0 + 16 * DH + 32);
    f32x4 s0 = __builtin_amdgcn_mfma_f32_16x16x32_bf16(k00, q0, zero, 0, 0, 0);
    s0 = __builtin_amdgcn_mfma_f32_16x16x32_bf16(k01, q1, s0, 0, 0, 0);
    f32x4 s1 = __builtin_amdgcn_mfma_f32_16x16x32_bf16(k10, q0, zero, 0, 0, 0);
    s1 = __builtin_amdgcn_mfma_f32_16x16x32_bf16(k11, q1, s1, 0, 0, 0);

    float a[8];
    if (step == nsteps - 1) {  // only the last step straddles the diagonal
      const int qrel = qbase + lr - kv - lg * 4;  // valid: (kv + lg*4 + r) <= q
#pragma unroll
      for (int r = 0; r < 4; r++) {
        a[r]     = (r <= qrel)      ? s0[r] : -__builtin_inff();
        a[4 + r] = (r + 16 <= qrel) ? s1[r] : -__builtin_inff();
      }
    } else {
#pragma unroll
      for (int r = 0; r < 4; r++) { a[r] = s0[r]; a[4 + r] = s1[r]; }
    }

    // ---- column max over 32 kv: in-lane tree + 2 shfl (lanes 16/32 apart share q) ----
    float mx = fmaxf(fmaxf(fmaxf(a[0], a[1]), fmaxf(a[2], a[3])),
                     fmaxf(fmaxf(a[4], a[5]), fmaxf(a[6], a[7])));
    mx = fmaxf(mx, __shfl_xor(mx, 16));
    mx = fmaxf(mx, __shfl_xor(mx, 32));
    const float mn = fmaxf(m, mx);
    const float corr = __builtin_amdgcn_exp2f(m - mn);  // first step: exp2(-inf)=0
    m = mn;

    float p[8];
#pragma unroll
    for (int r = 0; r < 8; r++) p[r] = __builtin_amdgcn_exp2f(a[r] - mn);
    float sum = ((p[0] + p[1]) + (p[2] + p[3])) + ((p[4] + p[5]) + (p[6] + p[7]));
    sum += __shfl_xor(sum, 16);
    sum += __shfl_xor(sum, 32);
    l = l * corr + sum;

    // ---- P^T -> LDS [q][kv], packed bf16 pairs ----
    const int wb = lr * 20 + lg * 2;  // u32 units; row stride 40 u16
    Plw[wb]     = pkbf(p[0], p[1]);
    Plw[wb + 1] = pkbf(p[2], p[3]);
    Plw[wb + 8] = pkbf(p[4], p[5]);
    Plw[wb + 9] = pkbf(p[6], p[7]);

    // ---- rescale O while LDS writes land ----
#pragma unroll
    for (int dt = 0; dt < 4; dt++)
#pragma unroll
      for (int r = 0; r < 4; r++) o[dt][r] *= corr;

    __builtin_amdgcn_wave_barrier();
    const bf16x8 pf = *(const bf16x8*)&Pl[lr * 40 + lg * 8];  // B-frag: col=q, k=kv
#pragma unroll
    for (int dt = 0; dt < 4; dt++) {
      bf16x8 vf = *(const bf16x8*)(Vt + ((size_t)bh * DH + dt * 16 + lr) * S_LEN + kv + lg * 8);
      o[dt] = __builtin_amdgcn_mfma_f32_16x16x32_bf16(vf, pf, o[dt], 0, 0, 0);  // O^T
    }
  }

  // ---- epilogue: O^T lane holds q=lr (col), d = dt*16 + lg*4 + r (rows) ----
  const int b = bh >> 4, h = bh & 15;
  const float rl = __builtin_amdgcn_rcpf(l);
  const size_t obase = ((size_t)b * S_LEN + qbase + lr) * DM + h * DH;
#pragma unroll
  for (int dt = 0; dt < 4; dt++) {
    u32x2 pk;
    pk.x = pkbf(o[dt][0] * rl, o[dt][1] * rl);
    pk.y = pkbf(o[dt][2] * rl, o[dt][3] * rl);
    *(u32x2*)(Oo + obase + dt * 16 + lg * 4) = pk;
  }
}

// ---------------- host launcher ----------------
extern "C" void kernel_launch(void* const* d_in, const int* in_sizes, int n_in,
                              void* d_out, int out_size, void* d_ws, size_t ws_size,
                              hipStream_t stream) {
  const float* x  = (const float*)d_in[0];
  const float* Wq = (const float*)d_in[1];
  const float* bq = (const float*)d_in[2];
  const float* Wk = (const float*)d_in[3];
  const float* bk = (const float*)d_in[4];
  const float* Wv = (const float*)d_in[5];
  const float* bv = (const float*)d_in[6];
  const float* Wo = (const float*)d_in[7];
  const float* bo = (const float*)d_in[8];

  char* ws = (char*)d_ws;
  u16* xb    = (u16*)(ws);                 // 8 MB  [4096,1024] bf16
  u16* wb    = (u16*)(ws + (8u << 20));    // 8 MB  Wq,Wk,Wv,Wo bf16
  u16* Qb    = (u16*)(ws + (16u << 20));   // 8 MB  [B,H,S,Dh]
  u16* Kb    = (u16*)(ws + (24u << 20));   // 8 MB  [B,H,S,Dh]
  u16* Vtb   = (u16*)(ws + (32u << 20));   // 8 MB  [B,H,Dh,S]
  u16* AOb   = (u16*)(ws + (40u << 20));   // 8 MB  [B*S, DM]
  float2* rt = (float2*)(ws + (48u << 20)); // 512 KB rope table

  convert_k<<<8192, 256, 0, stream>>>(x, Wq, Wk, Wv, Wo, xb, wb);
  rope_k<<<256, 256, 0, stream>>>(rt);
  gemm_k<<<768, 256, 0, stream>>>(xb, wb, wb + (1u << 20), wb + (2u << 20),
                                  bq, bk, bv, rt, Qb, Kb, Vtb, 0);
  attn_k<<<2048, 128, 0, stream>>>(Qb, Kb, Vtb, AOb);
  gemm_k<<<256, 256, 0, stream>>>(AOb, wb + (3u << 20), wb + (3u << 20), wb + (3u << 20),
                                  bo, bo, bo, rt, d_out, d_out, d_out, 3);
}